// Round 1
// baseline (47.394 us; speedup 1.0000x reference)
//
#include <hip/hip_runtime.h>

#define T_STEPS 256
#define TCHUNK  32
#define NCHUNK  (T_STEPS / TCHUNK)   // 8
#define BLOCK   256

__device__ __forceinline__ float sc_chain(float xc, float m1, float m2, float m3, float m4,
                                          float a1, float a2, float a3, float a4) {
    float n1 = 1.0f - xc * a1;
    float n2 = 1.0f - n1 * (a2 * m1);
    float n3 = 1.0f - n2 * (a3 * m2);
    float n4 = 1.0f - n3 * (a4 * m3);
    return 1.0f - n4 * m4;
}

__global__ __launch_bounds__(BLOCK) void sc_mul_chain_kernel(
    const float* __restrict__ x,
    const float* __restrict__ c1,
    const float* __restrict__ c2,
    const float* __restrict__ c3,
    const float* __restrict__ c4,
    float* __restrict__ out,
    int nv /* N/4 */, int vcblocks /* nv/BLOCK */)
{
    __shared__ float sc[4][TCHUNK];

    const int bid = blockIdx.x;
    const int vcb = bid % vcblocks;
    const int tc  = bid / vcblocks;
    const int t0  = tc * TCHUNK;

    // Stage the per-timestep constants for this chunk into LDS.
    if (threadIdx.x < 4 * TCHUNK) {
        const int which = threadIdx.x / TCHUNK;
        const int tt    = threadIdx.x % TCHUNK;
        const float* cp = (which == 0) ? c1 : (which == 1) ? c2 : (which == 2) ? c3 : c4;
        sc[which][tt] = cp[t0 + tt];
    }
    __syncthreads();

    const int vc = vcb * BLOCK + threadIdx.x;
    const float4* __restrict__ xv = (const float4*)x;
    float4* __restrict__ ov = (float4*)out;

    // Rolling delay registers: xm1 = x[t-1], ..., xm4 = x[t-4].
    float4 xm1, xm2, xm3, xm4;
    if (t0 == 0) {
        xm1 = xm2 = xm3 = xm4 = make_float4(0.f, 0.f, 0.f, 0.f);
    } else {
        xm1 = xv[(size_t)(t0 - 1) * nv + vc];
        xm2 = xv[(size_t)(t0 - 2) * nv + vc];
        xm3 = xv[(size_t)(t0 - 3) * nv + vc];
        xm4 = xv[(size_t)(t0 - 4) * nv + vc];
    }

    #pragma unroll 4
    for (int i = 0; i < TCHUNK; ++i) {
        const int t = t0 + i;
        const float4 xc = xv[(size_t)t * nv + vc];
        const float a1 = sc[0][i], a2 = sc[1][i], a3 = sc[2][i], a4 = sc[3][i];

        float4 o;
        o.x = sc_chain(xc.x, xm1.x, xm2.x, xm3.x, xm4.x, a1, a2, a3, a4);
        o.y = sc_chain(xc.y, xm1.y, xm2.y, xm3.y, xm4.y, a1, a2, a3, a4);
        o.z = sc_chain(xc.z, xm1.z, xm2.z, xm3.z, xm4.z, a1, a2, a3, a4);
        o.w = sc_chain(xc.w, xm1.w, xm2.w, xm3.w, xm4.w, a1, a2, a3, a4);

        ov[(size_t)t * nv + vc] = o;

        xm4 = xm3; xm3 = xm2; xm2 = xm1; xm1 = xc;
    }
}

extern "C" void kernel_launch(void* const* d_in, const int* in_sizes, int n_in,
                              void* d_out, int out_size, void* d_ws, size_t ws_size,
                              hipStream_t stream) {
    const float* x  = (const float*)d_in[0];
    const float* c1 = (const float*)d_in[1];
    const float* c2 = (const float*)d_in[2];
    const float* c3 = (const float*)d_in[3];
    const float* c4 = (const float*)d_in[4];
    float* out = (float*)d_out;

    const int n  = in_sizes[0] / T_STEPS;   // 131072
    const int nv = n / 4;                   // 32768
    const int vcblocks = nv / BLOCK;        // 128

    dim3 grid(vcblocks * NCHUNK);
    dim3 block(BLOCK);
    sc_mul_chain_kernel<<<grid, block, 0, stream>>>(x, c1, c2, c3, c4, out, nv, vcblocks);
}

// Round 2
// 46.099 us; speedup vs baseline: 1.0281x; 1.0281x over previous
//
#include <hip/hip_runtime.h>

#define T_STEPS 256
#define TCHUNK  64
#define NCHUNK  (T_STEPS / TCHUNK)   // 4
#define BLOCK   256

__device__ __forceinline__ float sc_chain(float xc, float m1, float m2, float m3, float m4,
                                          float a1, float a2, float a3, float a4) {
    float n1 = 1.0f - xc * a1;
    float n2 = 1.0f - n1 * (a2 * m1);
    float n3 = 1.0f - n2 * (a3 * m2);
    float n4 = 1.0f - n3 * (a4 * m3);
    return 1.0f - n4 * m4;
}

__global__ __launch_bounds__(BLOCK) void sc_mul_chain_kernel(
    const float* __restrict__ x,
    const float* __restrict__ c1,
    const float* __restrict__ c2,
    const float* __restrict__ c3,
    const float* __restrict__ c4,
    float* __restrict__ out,
    int nv /* N/4 */, int vcblocks /* nv/BLOCK */)
{
    __shared__ float sc[4][TCHUNK];

    const int bid = blockIdx.x;
    const int vcb = bid % vcblocks;
    const int tc  = bid / vcblocks;
    const int t0  = tc * TCHUNK;

    // Stage the per-timestep constants for this chunk into LDS.
    if (threadIdx.x < 4 * TCHUNK) {
        const int which = threadIdx.x / TCHUNK;
        const int tt    = threadIdx.x % TCHUNK;
        const float* cp = (which == 0) ? c1 : (which == 1) ? c2 : (which == 2) ? c3 : c4;
        sc[which][tt] = cp[t0 + tt];
    }
    __syncthreads();

    const int vc = vcb * BLOCK + threadIdx.x;
    const float4* __restrict__ xv = (const float4*)x;
    float4* __restrict__ ov = (float4*)out;

    // Rolling delay registers: xm1 = x[t-1], ..., xm4 = x[t-4].
    float4 xm1, xm2, xm3, xm4;
    if (t0 == 0) {
        xm1 = xm2 = xm3 = xm4 = make_float4(0.f, 0.f, 0.f, 0.f);
    } else {
        xm1 = xv[(size_t)(t0 - 1) * nv + vc];
        xm2 = xv[(size_t)(t0 - 2) * nv + vc];
        xm3 = xv[(size_t)(t0 - 3) * nv + vc];
        xm4 = xv[(size_t)(t0 - 4) * nv + vc];
    }

    #pragma unroll 8
    for (int i = 0; i < TCHUNK; ++i) {
        const int t = t0 + i;
        const float4 xc = xv[(size_t)t * nv + vc];
        const float a1 = sc[0][i], a2 = sc[1][i], a3 = sc[2][i], a4 = sc[3][i];

        float4 o;
        o.x = sc_chain(xc.x, xm1.x, xm2.x, xm3.x, xm4.x, a1, a2, a3, a4);
        o.y = sc_chain(xc.y, xm1.y, xm2.y, xm3.y, xm4.y, a1, a2, a3, a4);
        o.z = sc_chain(xc.z, xm1.z, xm2.z, xm3.z, xm4.z, a1, a2, a3, a4);
        o.w = sc_chain(xc.w, xm1.w, xm2.w, xm3.w, xm4.w, a1, a2, a3, a4);

        ov[(size_t)t * nv + vc] = o;

        xm4 = xm3; xm3 = xm2; xm2 = xm1; xm1 = xc;
    }
}

extern "C" void kernel_launch(void* const* d_in, const int* in_sizes, int n_in,
                              void* d_out, int out_size, void* d_ws, size_t ws_size,
                              hipStream_t stream) {
    const float* x  = (const float*)d_in[0];
    const float* c1 = (const float*)d_in[1];
    const float* c2 = (const float*)d_in[2];
    const float* c3 = (const float*)d_in[3];
    const float* c4 = (const float*)d_in[4];
    float* out = (float*)d_out;

    const int n  = in_sizes[0] / T_STEPS;   // 131072
    const int nv = n / 4;                   // 32768
    const int vcblocks = nv / BLOCK;        // 128

    dim3 grid(vcblocks * NCHUNK);
    dim3 block(BLOCK);
    sc_mul_chain_kernel<<<grid, block, 0, stream>>>(x, c1, c2, c3, c4, out, nv, vcblocks);
}